// Round 7
// baseline (27.008 us; speedup 1.0000x reference)
//
#include <hip/hip_runtime.h>
#include <math.h>

#define HH 512
#define WW 1024
#define RR 5
#define KK 11
#define TOPK 200

// ---- fused vote+nms tile: 64 wide x 32 tall, 512 threads ----
#define TW 64
#define TH 32
#define SVH (TH + 6)      // 38 vote rows (NMS halo 3)
#define SVW (TW + 6)      // 70 vote cols
#define CRH (TH + 16)     // 48 cr rows (vote halo 5 on top)
#define CRW (TW + 16)     // 80 cr cols
#define CRHA 52           // padded rows: grp*6+rr reaches 51 for grp=6
#define MAXPB 160         // per-block candidate bound (17*9=153 max minima)
#define NBUCK 256         // = vote grid size
#define CAP 1536          // kernel-B LDS compaction cap

// ws layout (bytes):
// [0 ..)               : counts int[NBUCK]
// [1024 ..)            : gcv float[NBUCK*MAXPB]
// [1024+4*NB*MPB ..)   : gci int[NBUCK*MAXPB]

__global__ __launch_bounds__(512) void vote_nms_kernel(const float* __restrict__ cr,
                                                       float* __restrict__ gcv,
                                                       int* __restrict__ gci,
                                                       int* __restrict__ counts, float ct) {
    __shared__ float2 s[CRHA][CRW + 2];   // 52 x 82 float2 = 34.1 KB
    __shared__ float sv[SVH][SVW + 2];    // 38 x 72 float  = 10.9 KB
    __shared__ int lcnt;
    __shared__ float lval[MAXPB];
    __shared__ int lidx[MAXPB];
    const int tid = threadIdx.x;
    const int bx = blockIdx.x * TW, by = blockIdx.y * TH;
    if (tid == 0) lcnt = 0;

    // Stage cr (48 x 80) region, origin (by-8, bx-8), zero-padded outside
    // image; rows 48..51 are dead padding (feed only invalid accumulators).
    for (int l = tid; l < CRHA * CRW; l += 512) {
        int r = l / CRW, c = l % CRW;
        int rs = min(r, CRH - 1);
        int gy = by - 8 + rs, gx = bx - 8 + c;
        bool ok = (gy >= 0) && (gy < HH) && (gx >= 0) && (gx < WW);
        float vx = ok ? cr[gy * WW + gx] : 0.0f;
        float vy = ok ? cr[HH * WW + gy * WW + gx] : 0.0f;
        s[r][c] = make_float2(vx, vy);
    }
    __syncthreads();

    // ---- vote phase: 70 cols x 7 groups of 6 rows = 2660 votes (1.30x) ----
    // thread -> (col, grp); sv row R = grp*6 + t (t=0..5), valid R < 38.
    // Reassociated 2-chain sums: safe, ~1e-5 perturbation vs 0.3 margin to
    // CENTER_THRESH; NMS equality compares only values computed here.
    const int col = tid % SVW;     // 0..69
    const int grp = tid / SVW;     // 0..7 (grp 7 idle)
    if (grp < 7) {
        float a[6] = {0.f, 0.f, 0.f, 0.f, 0.f, 0.f};
        float b[6] = {0.f, 0.f, 0.f, 0.f, 0.f, 0.f};
        #pragma unroll
        for (int rr = 0; rr < 16; ++rr) {           // staged row = grp*6 + rr
            #pragma unroll
            for (int ix = 0; ix < KK; ++ix) {
                const int ox = ix - 5;
                bool any = false;
                #pragma unroll
                for (int t = 0; t < 6; ++t) {
                    const int oy = rr - 5 - t;
                    if (oy >= -RR && oy <= RR && ox * ox + oy * oy <= RR * RR) any = true;
                }
                if (!any) continue;                  // compile-time elision
                float2 v = s[grp * 6 + rr][col + ix];
                float dx = (float)ox - v.x;          // shared across t
                float dx2 = dx * dx;
                #pragma unroll
                for (int t = 0; t < 6; ++t) {
                    const int oy = rr - 5 - t;
                    if (oy >= -RR && oy <= RR && ox * ox + oy * oy <= RR * RR) {
                        float dy = (float)oy - v.y;
                        float sq = __builtin_amdgcn_sqrtf(fmaf(dy, dy, dx2));
                        if (ix & 1) b[t] += sq; else a[t] += sq;
                    }
                }
            }
        }
        #pragma unroll
        for (int t = 0; t < 6; ++t) {
            int R = grp * 6 + t;
            if (R < SVH) {
                int gy = by - 3 + R, gx = bx - 3 + col;
                bool in = (gy >= 0) && (gy < HH) && (gx >= 0) && (gx < WW);
                // INF outside image == reference's inf-padded reduce_window
                sv[R][col] = in ? (a[t] + b[t]) / 81.0f + 1.0f : INFINITY;
            }
        }
    }
    __syncthreads();

    // ---- NMS phase: separable 7x7 min from LDS; 4-pixel column/thread ----
    {
        const int x = tid & 63;          // sv col of window start; output col bx+x
        const int g = tid >> 6;          // 0..7 -> output rows by+g*4 .. +3
        float r10[10], ctr[4];
        #pragma unroll
        for (int j = 0; j < 10; ++j) {
            const float* row = &sv[g * 4 + j][x];
            float m0 = fminf(row[0], row[1]);
            float m1 = fminf(row[2], row[3]);
            float m2 = fminf(row[4], row[5]);
            float m3 = row[6];
            if (j >= 3 && j < 7) ctr[j - 3] = row[3];
            r10[j] = fminf(fminf(m0, m1), fminf(m2, m3));
        }
        float p[9], q[7];
        #pragma unroll
        for (int j = 0; j < 9; ++j) p[j] = fminf(r10[j], r10[j + 1]);
        #pragma unroll
        for (int j = 0; j < 7; ++j) q[j] = fminf(p[j], p[j + 2]);
        #pragma unroll
        for (int t = 0; t < 4; ++t) {
            float m = fminf(q[t], q[t + 3]);
            float v = ctr[t];
            if (v == m && v < ct) {
                int sp = atomicAdd(&lcnt, 1);       // LDS atomic, block-local
                if (sp < MAXPB) { lval[sp] = v; lidx[sp] = (by + g * 4 + t) * WW + bx + x; }
            }
        }
    }
    __syncthreads();

    // ---- deterministic bucket write (no global atomics, no init needed) ----
    int bkt = blockIdx.y * gridDim.x + blockIdx.x;
    int cnt = min(lcnt, MAXPB);
    if (tid == 0) counts[bkt] = cnt;
    for (int i = tid; i < cnt; i += 512) {
        gcv[bkt * MAXPB + i] = lval[i];
        gci[bkt * MAXPB + i] = lidx[i];
    }
}

// Bucket compaction + replicated selection (cheap when M small) + instances.
__global__ __launch_bounds__(256) void inst_select_kernel(const float* __restrict__ fg,
                                                          const float* __restrict__ cr,
                                                          const float* __restrict__ gcv,
                                                          const int* __restrict__ gci,
                                                          const int* __restrict__ counts,
                                                          float* __restrict__ out) {
    __shared__ int s_pre[NBUCK];
    __shared__ float s_cv[CAP];
    __shared__ int s_ci[CAP];
    __shared__ float bv[256];
    __shared__ int bi[256];
    __shared__ int s_idx[TOPK];
    __shared__ float s_val[TOPK];
    __shared__ float s_selx[TOPK];
    __shared__ float s_sely[TOPK];
    const int tid = threadIdx.x;

    // ---- compact buckets into LDS via Hillis-Steele prefix scan ----
    int myc = counts[tid];
    s_pre[tid] = myc;
    __syncthreads();
    #pragma unroll
    for (int off = 1; off < NBUCK; off <<= 1) {
        int add = (tid >= off) ? s_pre[tid - off] : 0;
        __syncthreads();
        s_pre[tid] += add;
        __syncthreads();
    }
    int total = s_pre[NBUCK - 1];
    int M = min(total, CAP);
    int base = s_pre[tid] - myc;
    for (int j = 0; j < myc; ++j) {
        int p = base + j;
        if (p < CAP) { s_cv[p] = gcv[tid * MAXPB + j]; s_ci[p] = gci[tid * MAXPB + j]; }
    }
    __syncthreads();

    const int Mtop = (M < TOPK) ? M : TOPK;

    // k-th smallest by (val, idx) lexicographic = min over entries strictly
    // greater than the previously selected one (matches jax top_k tie-break).
    float lastv = -INFINITY;
    int lasti = -1;
    for (int k = 0; k < Mtop; ++k) {
        float bestv = INFINITY;
        int besti = 0x7fffffff;
        for (int j = tid; j < M; j += 256) {
            float cvj = s_cv[j];
            int cij = s_ci[j];
            if (cvj > lastv || (cvj == lastv && cij > lasti)) {
                if (cvj < bestv || (cvj == bestv && cij < besti)) { bestv = cvj; besti = cij; }
            }
        }
        bv[tid] = bestv; bi[tid] = besti;
        __syncthreads();
        for (int s = 128; s > 0; s >>= 1) {
            if (tid < s) {
                float ov = bv[tid + s]; int oi = bi[tid + s];
                if (ov < bv[tid] || (ov == bv[tid] && oi < bi[tid])) { bv[tid] = ov; bi[tid] = oi; }
            }
            __syncthreads();
        }
        lastv = bv[0]; lasti = bi[0];
        if (tid == 0) { s_val[k] = lastv; s_idx[k] = lasti; }
        __syncthreads();
    }

    // Parallel fill of remaining slots with the smallest non-candidate
    // indices (all non-candidates tie at -inf in top_k(-cand): ascending
    // index). rank r non-candidate index = fixed point of g = r + #{ci <= g}.
    for (int k = Mtop + tid; k < TOPK; k += 256) {
        int r = k - Mtop;
        int g = r, prev = -1;
        while (g != prev) {
            prev = g;
            int cnt2 = 0;
            for (int j = 0; j < M; ++j) cnt2 += (s_ci[j] <= g) ? 1 : 0;
            g = r + cnt2;
        }
        s_idx[k] = g;
        s_val[k] = INFINITY;
    }
    __syncthreads();

    for (int k = tid; k < TOPK; k += 256) {
        int idx = s_idx[k];
        s_sely[k] = (float)(idx >> 10);       // idx / W
        s_selx[k] = (float)(idx & (WW - 1));  // idx % W
    }
    __syncthreads();

    // block 0 writes coords + cerr outputs
    if (blockIdx.x == 0) {
        for (int k = tid; k < TOPK; k += 256) {
            out[HH * WW + 2 * k]     = s_sely[k];
            out[HH * WW + 2 * k + 1] = s_selx[k];
            out[HH * WW + 2 * TOPK + k] = (k < Mtop) ? s_val[k] : 0.0f;
        }
    }

    // ---- instance assignment: 4 pixels per thread, float4 I/O ----
    int idx4 = blockIdx.x * 256 + tid;     // float4 index
    float4 o = make_float4(0.f, 0.f, 0.f, 0.f);
    if (M > 0) {
        int pix0 = idx4 * 4;
        int y = pix0 >> 10;
        float4 f = ((const float4*)fg)[idx4];
        float4 cx0 = ((const float4*)cr)[idx4];
        float4 cy0 = ((const float4*)(cr + HH * WW))[idx4];
        float fgv[4] = {f.x, f.y, f.z, f.w};
        float crx[4] = {cx0.x, cx0.y, cx0.z, cx0.w};
        float cry[4] = {cy0.x, cy0.y, cy0.z, cy0.w};
        float res[4];
        #pragma unroll
        for (int t = 0; t < 4; ++t) {
            res[t] = 0.f;
            if (fgv[t] >= 0.5f) {
                int x = (pix0 + t) & (WW - 1);
                float px = (float)(x + 1) - crx[t];
                float py = (float)(y + 1) - cry[t];
                float best = INFINITY;
                int bk = 0;
                for (int k = 0; k < Mtop; ++k) {
                    float ddx = px - s_selx[k];
                    float ddy = py - s_sely[k];
                    float d = ddx * ddx + ddy * ddy;
                    if (d < best) { best = d; bk = k; }  // first-occurrence tie-break
                }
                res[t] = (float)(bk + 1);
            }
        }
        o = make_float4(res[0], res[1], res[2], res[3]);
    }
    ((float4*)out)[idx4] = o;
}

extern "C" void kernel_launch(void* const* d_in, const int* in_sizes, int n_in,
                              void* d_out, int out_size, void* d_ws, size_t ws_size,
                              hipStream_t stream) {
    const float* fg = (const float*)d_in[0];
    const float* cr = (const float*)d_in[1];
    float* out = (float*)d_out;

    char* ws = (char*)d_ws;
    int* counts = (int*)ws;
    float* gcv = (float*)(ws + 1024);
    int* gci = (int*)(ws + 1024 + 4 * NBUCK * MAXPB);

    // CENTER_THRESH = mean circle distance + 0.5
    double s = 0.0;
    int n = 0;
    for (int iy = 0; iy < KK; ++iy)
        for (int ix = 0; ix < KK; ++ix) {
            double dx = ix - RR, dy = iy - RR;
            double d = sqrt(dx * dx + dy * dy);
            if (d <= (double)RR) { s += d; n++; }
        }
    float ct = (float)(s / n + 0.5);

    dim3 vgrid(WW / TW, HH / TH);        // 16 x 16 = 256 blocks (1/CU)
    vote_nms_kernel<<<vgrid, 512, 0, stream>>>(cr, gcv, gci, counts, ct);
    inst_select_kernel<<<(HH * WW / 4) / 256, 256, 0, stream>>>(fg, cr, gcv, gci, counts, out);
}